// Round 12
// baseline (246.354 us; speedup 1.0000x reference)
//
#include <hip/hip_runtime.h>
#include <hip/hip_cooperative_groups.h>
#include <hip/hip_bf16.h>
#include <math.h>

namespace cg = cooperative_groups;

#define BB 4
#define NN 512
#define TT 24
#define NXF 8
#define HH 64
#define PRED 12
#define MM (BB*NN)   // 2048

typedef __attribute__((ext_vector_type(8))) short short8;
typedef __attribute__((ext_vector_type(4))) float f32x4;
typedef unsigned short ushort;

// ---- workspace layout (float offsets) — planes are 65536 f32 apart (R8-R10 bug fixed) ----
#define WS_H1THI   0         // 131072 bf16 = 65536 f32
#define WS_H1TLO   65536
#define WS_H2THI   131072
#define WS_H2TLO   196608
#define WS_HL      262144    // 131072 f32
#define WS_EL      393216
#define WS_ER      395264
#define WS_EL2     397312
#define WS_ER2     399360
#define WS_WCOMB   401408
#define WS_BCOMB   403456
#define WS_WHHFRAG 403712    // 16384 ushort = 8192 f32 -> ends 411904

#define LHS 72
#define LXS 40

__device__ inline float sigm(float x){ return 1.f/(1.f+__expf(-x)); }
__device__ inline float tanh_fast(float x){ float e=__expf(2.f*x); return 1.f - 2.f/(e+1.f); }
__device__ inline float gelu_exact(float x){ return 0.5f*x*(1.f+erff(x*0.70710678118654752440f)); }
__device__ inline ushort f2bu(float f){
    unsigned b=__float_as_uint(f);
    return (ushort)((b + 0x7FFFu + ((b>>16)&1u))>>16);
}
__device__ inline float bu2f(ushort u){ return __uint_as_float(((unsigned)u)<<16); }

__device__ inline void split8(const float* f, short8& hi, short8& lo){
    #pragma unroll
    for (int j = 0; j < 8; ++j){
        ushort h = f2bu(f[j]);
        hi[j] = (short)h;
        lo[j] = (short)f2bu(f[j] - bu2f(h));
    }
}

struct Params {
    const float *x; const int *ei; int E;
    const float *Wfc,*bfc,*W1,*al1,*ar1,*bias1,*W2,*al2,*ar2,*bias2;
    const float *Wih,*Whh,*bih,*bhh,*g_l,*b_l,*g_g,*b_g,*W_d,*b_d;
    ushort *H1Thi,*H1Tlo,*H2Thi,*H2Tlo;
    float *hl,*el,*er,*el2,*er2,*wcombG,*bcombG; ushort *whhfrag;
    float *out;
};

__global__ __launch_bounds__(256,2) void mega_kernel(Params P){
    __shared__ __align__(16) char smem[41344];
    cg::grid_group grid = cg::this_grid();
    const int t = threadIdx.x, blk = blockIdx.x;
    const int lane = t & 63, w = t >> 6, quad = lane >> 4, c16 = lane & 15;

    // ================= P0: gat1pre (8 rows/block, 256 blocks) + LSTM precomp (blk 248-255) =================
    {
        float* sw1  = (float*)smem;                     // 16384
        float* swfc = (float*)(smem+16384);             // 2048
        float* sb   = (float*)(smem+18432);             // 256
        float* sal  = (float*)(smem+18688);             // 256
        float* sar  = (float*)(smem+18944);             // 256
        float (*sx)[8]   = (float(*)[8])(smem+19200);   // 256
        float (*sxh)[68] = (float(*)[68])(smem+19456);  // 2176 -> 21632

        #pragma unroll
        for (int i=0;i<16;++i) sw1[t+256*i] = P.W1[t+256*i];
        swfc[t] = P.Wfc[t]; swfc[t+256] = P.Wfc[t+256];
        if (t<64) sb[t]=P.bfc[t];
        else if (t<128) sal[t-64]=P.al1[t-64];
        else if (t<192) sar[t-128]=P.ar1[t-128];
        if (t<64){ int rr=t>>3, f=t&7;
            sx[rr][f] = P.x[(size_t)(blk*8+rr)*(TT*NXF) + (TT-1)*NXF + f]; }
        __syncthreads();
        const int r = t>>6, h = t&63;
        #pragma unroll
        for (int p=0;p<2;++p){
            int row = p*4+r;
            float xh = sb[h];
            #pragma unroll
            for (int f=0; f<NXF; ++f) xh += sx[row][f]*swfc[f*HH+h];
            sxh[row][h] = xh;
        }
        __syncthreads();
        #pragma unroll
        for (int p=0;p<2;++p){
            int row = p*4+r; int m = blk*8+row;
            float acc = 0.f;
            const float4* xr = (const float4*)&sxh[row][0];
            #pragma unroll
            for (int k4=0;k4<16;++k4){
                float4 xv = xr[k4];
                acc += xv.x*sw1[(4*k4+0)*HH+h] + xv.y*sw1[(4*k4+1)*HH+h]
                     + xv.z*sw1[(4*k4+2)*HH+h] + xv.w*sw1[(4*k4+3)*HH+h];
            }
            int bb = m >> 9, ml = m & 511;
            ushort hu = f2bu(acc);
            P.H1Thi[((size_t)(bb*HH + h))*NN + ml] = hu;
            P.H1Tlo[((size_t)(bb*HH + h))*NN + ml] = f2bu(acc - bu2f(hu));
            float v1 = acc*sal[h], v2 = acc*sar[h];
            #pragma unroll
            for (int o=32;o;o>>=1){ v1 += __shfl_xor(v1,o); v2 += __shfl_xor(v2,o); }
            if (h==0){ P.el[m]=v1; P.er[m]=v2; }
        }
        if (blk >= 248){
            const int f = blk-248, ng = t;
            float accf=0.f, accb=0.f;
            const float* wr = P.Wih + ng*64;
            #pragma unroll
            for (int k=0;k<64;++k){ float wv=wr[k]; accf += P.Wfc[f*64+k]*wv; accb += P.bfc[k]*wv; }
            P.wcombG[f*256+ng] = accf;
            if (f==0) P.bcombG[ng] = accb + P.bih[ng] + P.bhh[ng];
            #pragma unroll
            for (int u=0;u<8;++u){
                int o = f*2048 + u*256 + t;
                int F = o>>9, ln=(o>>3)&63, j=o&7;
                int w_=F>>3, tt=(F>>1)&3, ks=F&1;
                int q=ln>>4, c=ln&15;
                int ngx=(w_+4*tt)*16 + c;
                P.whhfrag[o] = f2bu(P.Whh[ngx*64 + ks*32 + q*8 + j]);
            }
        }
    }
    grid.sync();

    // ================= P1: attn1+gat2pre (blk<128)  |  LSTM (blk>=128) =================
    if (blk >= 128){
        ushort* hbi = (ushort*)smem;              // [2][16*LHS] 4608
        ushort* hlo = (ushort*)(smem+4608);       // 4608
        ushort* xls = (ushort*)(smem+9216);       // TT*16*LXS*2 = 30720 -> 39936
        const int m0 = (blk-128)*16;
        {
            unsigned* h0 = (unsigned*)hbi;
            unsigned* l0 = (unsigned*)hlo;
            for (int i=t;i<2*16*LHS/2;i+=256){ h0[i]=0u; l0[i]=0u; }
            unsigned* xw = (unsigned*)xls;
            for (int i=t;i<TT*16*LXS/2;i+=256) xw[i]=0u;
        }
        short8 bw[4][2]; short8 bx[4]; float bc[4];
        #pragma unroll
        for (int tt=0;tt<4;++tt){
            const int ng = (w + 4*tt)*16 + c16;
            bc[tt] = P.bcombG[ng];
            #pragma unroll
            for (int ks=0;ks<2;++ks)
                bw[tt][ks] = *(const short8*)&P.whhfrag[(((w*4+tt)*2)+ks)*512 + lane*8];
            short8 vx = {0,0,0,0,0,0,0,0};
            if (quad == 0){
                #pragma unroll
                for (int j=0;j<8;++j) vx[j] = (short)f2bu(P.wcombG[j*256 + ng]);
            }
            bx[tt] = vx;
        }
        __syncthreads();
        for (int i=t;i<16*TT*NXF;i+=256){
            int r = i/(TT*NXF);
            int rem = i - r*(TT*NXF);
            int st = rem>>3, f = rem&7;
            xls[st*(16*LXS) + r*LXS + f] = f2bu(P.x[(size_t)(m0+r)*(TT*NXF) + rem]);
        }
        __syncthreads();

        float cst[4] = {0,0,0,0};
        float hf[4]  = {0,0,0,0};
        for (int st=0; st<TT; ++st){
            const int p = st & 1;
            const ushort* hb  = hbi + p*(16*LHS);
            const ushort* hl_ = hlo + p*(16*LHS);
            short8 ahi0 = *(const short8*)&hb[c16*LHS + quad*8];
            short8 ahi1 = *(const short8*)&hb[c16*LHS + 32 + quad*8];
            short8 alo0 = *(const short8*)&hl_[c16*LHS + quad*8];
            short8 alo1 = *(const short8*)&hl_[c16*LHS + 32 + quad*8];
            short8 ax   = *(const short8*)&xls[st*(16*LXS) + c16*LXS + quad*8];
            f32x4 acc[4];
            #pragma unroll
            for (int tt=0;tt<4;++tt){
                f32x4 a = {bc[tt], bc[tt], bc[tt], bc[tt]};
                a = __builtin_amdgcn_mfma_f32_16x16x32_bf16(ax,   bx[tt],    a, 0,0,0);
                a = __builtin_amdgcn_mfma_f32_16x16x32_bf16(ahi0, bw[tt][0], a, 0,0,0);
                a = __builtin_amdgcn_mfma_f32_16x16x32_bf16(ahi1, bw[tt][1], a, 0,0,0);
                a = __builtin_amdgcn_mfma_f32_16x16x32_bf16(alo0, bw[tt][0], a, 0,0,0);
                a = __builtin_amdgcn_mfma_f32_16x16x32_bf16(alo1, bw[tt][1], a, 0,0,0);
                acc[tt] = a;
            }
            ushort* ho   = hbi + (p^1)*(16*LHS);
            ushort* lo_o = hlo + (p^1)*(16*LHS);
            #pragma unroll
            for (int reg=0;reg<4;++reg){
                float gi = acc[0][reg], gf = acc[1][reg], gg = acc[2][reg], go = acc[3][reg];
                float cn = sigm(gf)*cst[reg] + sigm(gi)*tanh_fast(gg);
                cst[reg] = cn;
                float hn = sigm(go)*tanh_fast(cn);
                hf[reg] = hn;
                ushort hu = f2bu(hn);
                float lov = hn - bu2f(hu);
                int addr = (quad*4+reg)*LHS + w*16 + c16;
                ho[addr] = hu;
                lo_o[addr] = f2bu(lov);
            }
            __syncthreads();
        }
        #pragma unroll
        for (int reg=0;reg<4;++reg)
            P.hl[(size_t)(m0 + quad*4 + reg)*HH + w*16 + c16] = hf[reg];
    } else {
        // ---------- attn layer1 + gat2pre (R11-verified content) ----------
        unsigned (*smask)[16] = (unsigned(*)[16])smem;            // 1024
        float* er_s = (float*)(smem+1024);                        // 2048
        float* sal  = (float*)(smem+3072);                        // 256
        float* sar  = (float*)(smem+3328);                        // 256
        float (*alpha)[516] = (float(*)[516])(smem+3584);         // 33024 -> 36608
        float (*xh2)[68] = (float(*)[68])(smem+36608);            // 4352 -> 40960

        const int b = blk>>5, m0 = (blk&31)*16;
        const int l = lane;
        if (t < 64) sal[t] = P.al2[t]; else if (t < 128) sar[t-64] = P.ar2[t-64];
        ((unsigned*)smask)[t] = 0;
        er_s[t] = P.er[b*NN+t];
        er_s[t+256] = P.er[b*NN+t+256];
        __syncthreads();
        for (int e=t;e<P.E;e+=256){
            int s = P.ei[e];
            unsigned rl = (unsigned)(s-m0);
            if (rl<16u){ int d = P.ei[P.E+e]; atomicOr(&smask[rl][d>>5], 1u<<(d&31)); }
        }
        __syncthreads();
        for (int q=0;q<4;++q){
            const int i = w*4+q;
            const float elv = P.el[b*NN+m0+i];
            float e8[8]; unsigned mk=0; float mx=-1e30f;
            #pragma unroll
            for (int j=0;j<8;++j){
                int n = l + 64*j;
                float ev = elv + er_s[n];
                ev = ev >= 0.f ? ev : 0.2f*ev;
                unsigned mb = (smask[i][(l>>5) + 2*j] >> (l&31)) & 1u;
                e8[j] = ev;
                if (mb){ mk |= (1u<<j); mx = fmaxf(mx, ev); }
            }
            #pragma unroll
            for (int o=32;o;o>>=1) mx = fmaxf(mx, __shfl_xor(mx,o));
            float s = 0.f;
            #pragma unroll
            for (int j=0;j<8;++j){
                float pp = ((mk>>j)&1u) ? __expf(e8[j]-mx) : 0.f;
                e8[j] = pp; s += pp;
            }
            #pragma unroll
            for (int o=32;o;o>>=1) s += __shfl_xor(s,o);
            const float inv = 1.f/s;
            #pragma unroll
            for (int j=0;j<8;++j) alpha[i][l + 64*j] = e8[j]*inv;
        }
        __syncthreads();
        const ushort* bhp = P.H1Thi + ((size_t)(b*HH + w*16 + c16))*NN;
        const ushort* blp = P.H1Tlo + ((size_t)(b*HH + w*16 + c16))*NN;
        f32x4 acc = {0.f,0.f,0.f,0.f};
        for (int k0=0;k0<NN;k0+=32){
            const float* ap = &alpha[c16][k0 + quad*8];
            float4 a0 = *(const float4*)ap;
            float4 a1 = *(const float4*)(ap + 4);
            float af[8] = {a0.x,a0.y,a0.z,a0.w,a1.x,a1.y,a1.z,a1.w};
            short8 a_h, a_l;
            split8(af, a_h, a_l);
            short8 b_h = *(const short8*)&bhp[k0 + quad*8];
            short8 b_l = *(const short8*)&blp[k0 + quad*8];
            acc = __builtin_amdgcn_mfma_f32_16x16x32_bf16(a_h, b_h, acc, 0,0,0);
            acc = __builtin_amdgcn_mfma_f32_16x16x32_bf16(a_l, b_h, acc, 0,0,0);
            acc = __builtin_amdgcn_mfma_f32_16x16x32_bf16(a_h, b_l, acc, 0,0,0);
        }
        __syncthreads();   // alpha dead
        {
            const int h = w*16 + c16;
            const float bv = P.bias1[h];
            #pragma unroll
            for (int reg=0;reg<4;++reg)
                xh2[quad*4+reg][h] = gelu_exact(acc[reg]+bv);
        }
        float* sw2 = (float*)(smem+3584);   // overlay alpha
        #pragma unroll
        for (int i=0;i<16;++i) sw2[t+256*i] = P.W2[t+256*i];
        __syncthreads();
        {
            const int h = l;
            for (int q=0;q<4;++q){
                const int i = w + 4*q;
                float acc2 = 0.f;
                const float4* xr = (const float4*)&xh2[i][0];
                #pragma unroll
                for (int k4=0;k4<16;++k4){
                    float4 xv = xr[k4];
                    acc2 += xv.x*sw2[(4*k4+0)*HH+h] + xv.y*sw2[(4*k4+1)*HH+h]
                          + xv.z*sw2[(4*k4+2)*HH+h] + xv.w*sw2[(4*k4+3)*HH+h];
                }
                const int m = b*NN + m0 + i;
                ushort hu = f2bu(acc2);
                P.H2Thi[((size_t)(b*HH+h))*NN + (m0+i)] = hu;
                P.H2Tlo[((size_t)(b*HH+h))*NN + (m0+i)] = f2bu(acc2 - bu2f(hu));
                float v1 = acc2*sal[h], v2 = acc2*sar[h];
                #pragma unroll
                for (int o=32;o;o>>=1){ v1 += __shfl_xor(v1,o); v2 += __shfl_xor(v2,o); }
                if (h==0){ P.el2[m]=v1; P.er2[m]=v2; }
            }
        }
    }
    grid.sync();

    // ================= P2: attn layer2 + LN + decode (blk<128) =================
    if (blk < 128){
        unsigned (*smask)[16] = (unsigned(*)[16])smem;
        float* er_s = (float*)(smem+1024);
        float (*alpha)[516] = (float(*)[516])(smem+3584);         // -> 36608

        const int b = blk>>5, m0 = (blk&31)*16;
        const int l = lane;
        ((unsigned*)smask)[t] = 0;
        er_s[t] = P.er2[b*NN+t];
        er_s[t+256] = P.er2[b*NN+t+256];
        __syncthreads();
        for (int e=t;e<P.E;e+=256){
            int s = P.ei[e];
            unsigned rl = (unsigned)(s-m0);
            if (rl<16u){ int d = P.ei[P.E+e]; atomicOr(&smask[rl][d>>5], 1u<<(d&31)); }
        }
        __syncthreads();
        for (int q=0;q<4;++q){
            const int i = w*4+q;
            const float elv = P.el2[b*NN+m0+i];
            float e8[8]; unsigned mk=0; float mx=-1e30f;
            #pragma unroll
            for (int j=0;j<8;++j){
                int n = l + 64*j;
                float ev = elv + er_s[n];
                ev = ev >= 0.f ? ev : 0.2f*ev;
                unsigned mb = (smask[i][(l>>5) + 2*j] >> (l&31)) & 1u;
                e8[j] = ev;
                if (mb){ mk |= (1u<<j); mx = fmaxf(mx, ev); }
            }
            #pragma unroll
            for (int o=32;o;o>>=1) mx = fmaxf(mx, __shfl_xor(mx,o));
            float s = 0.f;
            #pragma unroll
            for (int j=0;j<8;++j){
                float pp = ((mk>>j)&1u) ? __expf(e8[j]-mx) : 0.f;
                e8[j] = pp; s += pp;
            }
            #pragma unroll
            for (int o=32;o;o>>=1) s += __shfl_xor(s,o);
            const float inv = 1.f/s;
            #pragma unroll
            for (int j=0;j<8;++j) alpha[i][l + 64*j] = e8[j]*inv;
        }
        __syncthreads();
        const ushort* bhp = P.H2Thi + ((size_t)(b*HH + w*16 + c16))*NN;
        const ushort* blp = P.H2Tlo + ((size_t)(b*HH + w*16 + c16))*NN;
        f32x4 acc = {0.f,0.f,0.f,0.f};
        for (int k0=0;k0<NN;k0+=32){
            const float* ap = &alpha[c16][k0 + quad*8];
            float4 a0 = *(const float4*)ap;
            float4 a1 = *(const float4*)(ap + 4);
            float af[8] = {a0.x,a0.y,a0.z,a0.w,a1.x,a1.y,a1.z,a1.w};
            short8 a_h, a_l;
            split8(af, a_h, a_l);
            short8 b_h = *(const short8*)&bhp[k0 + quad*8];
            short8 b_l = *(const short8*)&blp[k0 + quad*8];
            acc = __builtin_amdgcn_mfma_f32_16x16x32_bf16(a_h, b_h, acc, 0,0,0);
            acc = __builtin_amdgcn_mfma_f32_16x16x32_bf16(a_l, b_h, acc, 0,0,0);
            acc = __builtin_amdgcn_mfma_f32_16x16x32_bf16(a_h, b_l, acc, 0,0,0);
        }
        __syncthreads();   // alpha dead
        float* sg2  = (float*)(smem+3584);
        float* sdec = (float*)(smem+20224);
        {
            const int h = w*16 + c16;
            const float bv = P.bias2[h];
            #pragma unroll
            for (int reg=0;reg<4;++reg)
                sg2[(quad*4+reg)*HH + h] = gelu_exact(acc[reg]+bv);
        }
        __syncthreads();
        const int gbase = b*NN + m0;
        {
            const int h = l;
            for (int q=0;q<4;++q){
                const int ml = w*4+q;
                float gv = sg2[ml*HH+h];
                float lv = P.hl[(size_t)(gbase+ml)*HH + h];

                float s1 = gv;
                #pragma unroll
                for (int o=32;o;o>>=1) s1 += __shfl_xor(s1,o);
                float dg = gv - s1*(1.f/64.f);
                float v1 = dg*dg;
                #pragma unroll
                for (int o=32;o;o>>=1) v1 += __shfl_xor(v1,o);
                float lng = dg*rsqrtf(v1*(1.f/64.f)+1e-5f)*P.g_g[h] + P.b_g[h];

                float s2 = lv;
                #pragma unroll
                for (int o=32;o;o>>=1) s2 += __shfl_xor(s2,o);
                float dl = lv - s2*(1.f/64.f);
                float v2 = dl*dl;
                #pragma unroll
                for (int o=32;o;o>>=1) v2 += __shfl_xor(v2,o);
                float lnl = dl*rsqrtf(v2*(1.f/64.f)+1e-5f)*P.g_l[h] + P.b_l[h];

                sdec[ml*HH+h] = lng + lnl;
            }
        }
        __syncthreads();
        if (t < 16*PRED){
            int rr = t/PRED, pp = t - rr*PRED;
            float a = P.b_d[pp];
            #pragma unroll
            for (int k=0;k<HH;++k) a += sdec[rr*HH+k]*P.W_d[k*PRED+pp];
            P.out[(size_t)(gbase+rr)*PRED+pp] = a;
        }
    }
}

extern "C" void kernel_launch(void* const* d_in, const int* in_sizes, int n_in,
                              void* d_out, int out_size, void* d_ws, size_t ws_size,
                              hipStream_t stream){
    float* ws = (float*)d_ws;
    Params prm;
    prm.x    = (const float*)d_in[0];
    prm.ei   = (const int*)  d_in[1];
    prm.E    = in_sizes[1]/2;
    prm.Wfc  = (const float*)d_in[2];
    prm.bfc  = (const float*)d_in[3];
    prm.W1   = (const float*)d_in[4];
    prm.al1  = (const float*)d_in[5];
    prm.ar1  = (const float*)d_in[6];
    prm.bias1= (const float*)d_in[7];
    prm.W2   = (const float*)d_in[8];
    prm.al2  = (const float*)d_in[9];
    prm.ar2  = (const float*)d_in[10];
    prm.bias2= (const float*)d_in[11];
    prm.Wih  = (const float*)d_in[12];
    prm.Whh  = (const float*)d_in[13];
    prm.bih  = (const float*)d_in[14];
    prm.bhh  = (const float*)d_in[15];
    prm.g_l  = (const float*)d_in[16];
    prm.b_l  = (const float*)d_in[17];
    prm.g_g  = (const float*)d_in[18];
    prm.b_g  = (const float*)d_in[19];
    prm.W_d  = (const float*)d_in[20];
    prm.b_d  = (const float*)d_in[21];
    prm.H1Thi = (ushort*)(ws + WS_H1THI);
    prm.H1Tlo = (ushort*)(ws + WS_H1TLO);
    prm.H2Thi = (ushort*)(ws + WS_H2THI);
    prm.H2Tlo = (ushort*)(ws + WS_H2TLO);
    prm.hl    = ws + WS_HL;
    prm.el    = ws + WS_EL;
    prm.er    = ws + WS_ER;
    prm.el2   = ws + WS_EL2;
    prm.er2   = ws + WS_ER2;
    prm.wcombG= ws + WS_WCOMB;
    prm.bcombG= ws + WS_BCOMB;
    prm.whhfrag = (ushort*)(ws + WS_WHHFRAG);
    prm.out   = (float*)d_out;

    void* args[] = { &prm };
    hipLaunchCooperativeKernel((void*)mega_kernel, dim3(256), dim3(256), args, 0, stream);
}